// Round 3
// baseline (373.720 us; speedup 1.0000x reference)
//
#include <hip/hip_runtime.h>
#include <hip/hip_bf16.h>

#define N_NODES 100000
#define N_EDGES 600000
#define D_IN 128
#define D_OUT 512
#define CAP 40        // bucket capacity per node (Poisson(6): P(deg>=40) ~ 1e-20)
#define OVF_CAP 1024

typedef __bf16 bf16x8 __attribute__((ext_vector_type(8)));
typedef __bf16 bf16x2 __attribute__((ext_vector_type(2)));
typedef float f32x4 __attribute__((ext_vector_type(4)));

// ---- workspace layout (bytes) ----
// h_bf16 : [0, 25,600,000)                N_NODES*128*2
// cnt    : [25,600,000, 26,000,000)       N_NODES*4
// ovf_cnt: [26,000,000, 26,000,016)       (memset covers cnt+ovf_cnt in one go)
// ovf    : [26,000,016, 26,008,208)       OVF_CAP * int2
// bucket : [26,008,208, 42,008,208)       N_NODES*CAP*4
// xb     : [42,008,208, 67,608,208)       N_NODES*128*2   (x in bf16, gather table)
// wb     : [67,608,208, 67,739,280)       512*128*2       (W in bf16)
#define OFF_CNT   25600000
#define OFF_OVFC  26000000
#define OFF_OVF   26000016
#define OFF_BUCK  26008208
#define OFF_XB    42008208
#define OFF_WB    67608208

__device__ inline bf16x8 cvt8(float4 v0, float4 v1) {
    bf16x8 u = { (__bf16)v0.x, (__bf16)v0.y, (__bf16)v0.z, (__bf16)v0.w,
                 (__bf16)v1.x, (__bf16)v1.y, (__bf16)v1.z, (__bf16)v1.w };
    return u;
}

// ---------------- kernel 1: buckets + x->bf16 + W->bf16 (fused) -------------
// blocks [0,EB): per-edge bucket build (scatter atomics)
// blocks [EB,EB+XB): x fp32 -> bf16 streaming convert (2048 elems/block, exact)
// blocks [EB+XB,EB+XB+WBK): W fp32 -> bf16 (exact)
#define EB  2344   // ceil(600000/256)
#define XB  6250   // 100000*128 / 2048
#define WBK 32     // 512*128 / 2048
__global__ void k_bucket_cvt(const int* __restrict__ ei, const float* __restrict__ x,
                             const float* __restrict__ W, int* __restrict__ cnt,
                             int* __restrict__ bucket, int* __restrict__ ovf_cnt,
                             int2* __restrict__ ovf, __bf16* __restrict__ xb,
                             __bf16* __restrict__ wb) {
    int b = blockIdx.x;
    if (b < EB) {
        int e = b * 256 + threadIdx.x;
        if (e >= N_EDGES) return;
        int r = ei[e];            // destination
        int c = ei[N_EDGES + e];  // source
        int slot = atomicAdd(&cnt[r], 1);
        if (slot < CAP) {
            bucket[(size_t)r * CAP + slot] = c;
        } else {
            int oi = atomicAdd(ovf_cnt, 1);
            if (oi < OVF_CAP) ovf[oi] = make_int2(r, c);
        }
    } else if (b < EB + XB) {
        size_t i = (size_t)(b - EB) * 2048 + threadIdx.x * 8;
        float4 v0 = *(const float4*)(x + i);
        float4 v1 = *(const float4*)(x + i + 4);
        *(bf16x8*)(xb + i) = cvt8(v0, v1);
    } else {
        size_t i = (size_t)(b - EB - XB) * 2048 + threadIdx.x * 8;
        float4 v0 = *(const float4*)(W + i);
        float4 v1 = *(const float4*)(W + i + 4);
        *(bf16x8*)(wb + i) = cvt8(v0, v1);
    }
}

// ---------------- kernel 2: h[r] = bf16( x[r] + sum_{c} xb[c] ) -------------
// one wave per node; lane holds 2 feature slots. Residual read fp32 (exact),
// neighbor gathers from the bf16 table (256 B/row, half the L3 traffic).
// Bucket list: ONE masked vector load + v_readlane broadcast; 4-deep gather.
__global__ void k_agg(const float* __restrict__ x, const __bf16* __restrict__ xb,
                      const int* __restrict__ cnt, const int* __restrict__ bucket,
                      const int* __restrict__ ovf_cnt, const int2* __restrict__ ovf,
                      __bf16* __restrict__ h) {
    int gw = (blockIdx.x * blockDim.x + threadIdx.x) >> 6;  // wave id = node
    if (gw >= N_NODES) return;
    int lane = threadIdx.x & 63;
    const float2* xr = (const float2*)x;
    const unsigned int* xbu = (const unsigned int*)xb;  // bf16 pair per lane

    float2 a0 = xr[(size_t)gw * 64 + lane];  // residual x[gw] (fp32)
    float ax1 = 0.f, ay1 = 0.f, ax2 = 0.f, ay2 = 0.f, ax3 = 0.f, ay3 = 0.f;

    int deg = __builtin_amdgcn_readfirstlane(cnt[gw]);
    int dmin = deg < CAP ? deg : CAP;
    const int* bk = bucket + (size_t)gw * CAP;

    int myc = (lane < dmin) ? bk[lane] : 0;

    int d = 0;
    for (; d + 3 < dmin; d += 4) {
        int c0 = __builtin_amdgcn_readlane(myc, d);
        int c1 = __builtin_amdgcn_readlane(myc, d + 1);
        int c2 = __builtin_amdgcn_readlane(myc, d + 2);
        int c3 = __builtin_amdgcn_readlane(myc, d + 3);
        unsigned int u0 = xbu[(size_t)c0 * 64 + lane];
        unsigned int u1 = xbu[(size_t)c1 * 64 + lane];
        unsigned int u2 = xbu[(size_t)c2 * 64 + lane];
        unsigned int u3 = xbu[(size_t)c3 * 64 + lane];
        a0.x += __uint_as_float(u0 << 16);
        a0.y += __uint_as_float(u0 & 0xffff0000u);
        ax1  += __uint_as_float(u1 << 16);
        ay1  += __uint_as_float(u1 & 0xffff0000u);
        ax2  += __uint_as_float(u2 << 16);
        ay2  += __uint_as_float(u2 & 0xffff0000u);
        ax3  += __uint_as_float(u3 << 16);
        ay3  += __uint_as_float(u3 & 0xffff0000u);
    }
    for (; d < dmin; ++d) {
        int c0 = __builtin_amdgcn_readlane(myc, d);
        unsigned int u0 = xbu[(size_t)c0 * 64 + lane];
        a0.x += __uint_as_float(u0 << 16);
        a0.y += __uint_as_float(u0 & 0xffff0000u);
    }
    a0.x += ax1 + ax2 + ax3;
    a0.y += ay1 + ay2 + ay3;

    if (deg > CAP) {  // statistically never; correctness fallback (fp32 x)
        int n = *ovf_cnt;
        if (n > OVF_CAP) n = OVF_CAP;
        for (int i = 0; i < n; ++i) {
            int2 e = ovf[i];
            if (e.x == gw) {
                float2 v = xr[(size_t)e.y * 64 + lane];
                a0.x += v.x; a0.y += v.y;
            }
        }
    }

    bf16x2 o = { (__bf16)a0.x, (__bf16)a0.y };
    ((bf16x2*)h)[(size_t)gw * 64 + lane] = o;
}

// ---------------- kernel 3: out = h @ W^T + b (bf16 MFMA) -------------------
// BM=128, BN=128, 512 thr / 8 waves, XCD-bijective swizzle. B reads the
// pre-converted bf16 W (16-B loads, no per-block cvt).
#define BM 128
#define BN 128
#define LDA 136   // +8 pad: row stride 272B -> 2-way bank alias (free per m136)
#define LDB 136
#define NWG 3128  // 782 m-panels * 4 n-panels; 3128 = 8*391 (bijective swizzle)

__launch_bounds__(512, 4)
__global__ void k_gemm(const __bf16* __restrict__ h, const __bf16* __restrict__ wb,
                       const float* __restrict__ bias, float* __restrict__ out) {
    __shared__ __bf16 As[BM * LDA];  // 34816 B
    __shared__ __bf16 Bs[BN * LDB];  // 34816 B  (total ~70KB -> 2 blocks/CU)

    int tid = threadIdx.x;

    int bid = blockIdx.x;
    int wg = (bid & 7) * (NWG / 8) + (bid >> 3);
    int m0 = (wg >> 2) * BM;
    int n0 = (wg & 3) * BN;

    // stage A: 128x128 bf16, 16B loads
    #pragma unroll
    for (int it = 0; it < 4; ++it) {
        int i = tid + it * 512;
        int r = i >> 4;
        int c = (i & 15) << 3;
        int gr = m0 + r;
        if (gr > N_NODES - 1) gr = N_NODES - 1;
        *(bf16x8*)&As[r * LDA + c] = *(const bf16x8*)(h + (size_t)gr * D_IN + c);
    }
    // stage B: 128x128 bf16 W slice, 16B loads
    #pragma unroll
    for (int it = 0; it < 4; ++it) {
        int i = tid + it * 512;
        int r = i >> 4;
        int c = (i & 15) << 3;
        *(bf16x8*)&Bs[r * LDB + c] = *(const bf16x8*)(wb + (size_t)(n0 + r) * D_IN + c);
    }
    __syncthreads();

    int lane = tid & 63;
    int wave = tid >> 6;   // 0..7
    int wm = wave & 1;     // 2 waves along m (64 rows each)
    int wn = wave >> 1;    // 4 waves along n (32 cols each)
    int quad = lane >> 4;
    int l16 = lane & 15;

    f32x4 acc[4][2] = {};

    const __bf16* Abase = &As[(wm * 64 + l16) * LDA + quad * 8];
    const __bf16* Bbase = &Bs[(wn * 32 + l16) * LDB + quad * 8];

    #pragma unroll
    for (int ks = 0; ks < 4; ++ks) {
        bf16x8 a0 = *(const bf16x8*)(Abase + ks * 32);
        bf16x8 a1 = *(const bf16x8*)(Abase + 16 * LDA + ks * 32);
        bf16x8 a2 = *(const bf16x8*)(Abase + 32 * LDA + ks * 32);
        bf16x8 a3 = *(const bf16x8*)(Abase + 48 * LDA + ks * 32);
        bf16x8 b0 = *(const bf16x8*)(Bbase + ks * 32);
        bf16x8 b1 = *(const bf16x8*)(Bbase + 16 * LDB + ks * 32);
        acc[0][0] = __builtin_amdgcn_mfma_f32_16x16x32_bf16(a0, b0, acc[0][0], 0, 0, 0);
        acc[0][1] = __builtin_amdgcn_mfma_f32_16x16x32_bf16(a0, b1, acc[0][1], 0, 0, 0);
        acc[1][0] = __builtin_amdgcn_mfma_f32_16x16x32_bf16(a1, b0, acc[1][0], 0, 0, 0);
        acc[1][1] = __builtin_amdgcn_mfma_f32_16x16x32_bf16(a1, b1, acc[1][1], 0, 0, 0);
        acc[2][0] = __builtin_amdgcn_mfma_f32_16x16x32_bf16(a2, b0, acc[2][0], 0, 0, 0);
        acc[2][1] = __builtin_amdgcn_mfma_f32_16x16x32_bf16(a2, b1, acc[2][1], 0, 0, 0);
        acc[3][0] = __builtin_amdgcn_mfma_f32_16x16x32_bf16(a3, b0, acc[3][0], 0, 0, 0);
        acc[3][1] = __builtin_amdgcn_mfma_f32_16x16x32_bf16(a3, b1, acc[3][1], 0, 0, 0);
    }

    float bias0 = bias[n0 + wn * 32 + l16];
    float bias1 = bias[n0 + wn * 32 + 16 + l16];
    #pragma unroll
    for (int mt = 0; mt < 4; ++mt) {
        int mrow = m0 + wm * 64 + mt * 16 + quad * 4;
        #pragma unroll
        for (int nt = 0; nt < 2; ++nt) {
            int ncol = n0 + wn * 32 + nt * 16 + l16;
            float bv = nt ? bias1 : bias0;
            #pragma unroll
            for (int rg = 0; rg < 4; ++rg) {
                int m = mrow + rg;
                if (m < N_NODES)
                    out[(size_t)m * D_OUT + ncol] = acc[mt][nt][rg] + bv;
            }
        }
    }
}

extern "C" void kernel_launch(void* const* d_in, const int* in_sizes, int n_in,
                              void* d_out, int out_size, void* d_ws, size_t ws_size,
                              hipStream_t stream) {
    const float* x  = (const float*)d_in[0];
    const int*   ei = (const int*)d_in[1];
    const float* W  = (const float*)d_in[2];
    const float* b  = (const float*)d_in[3];
    float* out = (float*)d_out;

    char* ws = (char*)d_ws;
    __bf16* h    = (__bf16*)ws;
    int* cnt     = (int*)(ws + OFF_CNT);
    int* ovf_cnt = (int*)(ws + OFF_OVFC);
    int2* ovf    = (int2*)(ws + OFF_OVF);
    int* bucket  = (int*)(ws + OFF_BUCK);
    __bf16* xb   = (__bf16*)(ws + OFF_XB);
    __bf16* wb   = (__bf16*)(ws + OFF_WB);

    // zero cnt + ovf_cnt (contiguous region)
    hipMemsetAsync(cnt, 0, (OFF_OVFC - OFF_CNT) + 16, stream);

    k_bucket_cvt<<<EB + XB + WBK, 256, 0, stream>>>(ei, x, W, cnt, bucket,
                                                    ovf_cnt, ovf, xb, wb);
    k_agg<<<(N_NODES * 64 + 255) / 256, 256, 0, stream>>>(x, xb, cnt, bucket,
                                                          ovf_cnt, ovf, h);
    k_gemm<<<NWG, 512, 0, stream>>>(h, wb, b, out);
}

// Round 5
// 351.680 us; speedup vs baseline: 1.0627x; 1.0627x over previous
//
#include <hip/hip_runtime.h>
#include <hip/hip_bf16.h>

#define N_NODES 100000
#define N_EDGES 600000
#define D_IN 128
#define D_OUT 512
#define CAP 40        // bucket capacity per node (Poisson(6): P(deg>=40) ~ 1e-20)
#define OVF_CAP 1024

typedef __bf16 bf16x8 __attribute__((ext_vector_type(8)));
typedef __bf16 bf16x2 __attribute__((ext_vector_type(2)));
typedef float f32x4 __attribute__((ext_vector_type(4)));

// ---- workspace layout (bytes) ----
// h_bf16 : [0, 25,600,000)                N_NODES*128*2
// cnt    : [25,600,000, 26,000,000)       N_NODES*4
// ovf_cnt: [26,000,000, 26,000,016)       (memset covers cnt+ovf_cnt in one go)
// ovf    : [26,000,016, 26,008,208)       OVF_CAP * int2
// bucket : [26,008,208, 42,008,208)       N_NODES*CAP*4
// xb     : [42,008,208, 67,608,208)       N_NODES*128*2   (x in bf16, gather table)
// wb     : [67,608,208, 67,739,280)       512*128*2       (W in bf16)
#define OFF_CNT   25600000
#define OFF_OVFC  26000000
#define OFF_OVF   26000016
#define OFF_BUCK  26008208
#define OFF_XB    42008208
#define OFF_WB    67608208

__device__ inline bf16x8 cvt8(float4 v0, float4 v1) {
    bf16x8 u = { (__bf16)v0.x, (__bf16)v0.y, (__bf16)v0.z, (__bf16)v0.w,
                 (__bf16)v1.x, (__bf16)v1.y, (__bf16)v1.z, (__bf16)v1.w };
    return u;
}

__device__ inline float blo(unsigned int u) { return __uint_as_float(u << 16); }
__device__ inline float bhi(unsigned int u) { return __uint_as_float(u & 0xffff0000u); }

// ---------------- kernel 1: buckets + x->bf16 + W->bf16 (fused) -------------
#define EB  2344   // ceil(600000/256)
#define XB  6250   // 100000*128 / 2048
#define WBK 32     // 512*128 / 2048
__global__ void k_bucket_cvt(const int* __restrict__ ei, const float* __restrict__ x,
                             const float* __restrict__ W, int* __restrict__ cnt,
                             int* __restrict__ bucket, int* __restrict__ ovf_cnt,
                             int2* __restrict__ ovf, __bf16* __restrict__ xb,
                             __bf16* __restrict__ wb) {
    int b = blockIdx.x;
    if (b < EB) {
        int e = b * 256 + threadIdx.x;
        if (e >= N_EDGES) return;
        int r = ei[e];            // destination
        int c = ei[N_EDGES + e];  // source
        int slot = atomicAdd(&cnt[r], 1);
        if (slot < CAP) {
            bucket[(size_t)r * CAP + slot] = c;
        } else {
            int oi = atomicAdd(ovf_cnt, 1);
            if (oi < OVF_CAP) ovf[oi] = make_int2(r, c);
        }
    } else if (b < EB + XB) {
        size_t i = (size_t)(b - EB) * 2048 + threadIdx.x * 8;
        float4 v0 = *(const float4*)(x + i);
        float4 v1 = *(const float4*)(x + i + 4);
        *(bf16x8*)(xb + i) = cvt8(v0, v1);
    } else {
        size_t i = (size_t)(b - EB - XB) * 2048 + threadIdx.x * 8;
        float4 v0 = *(const float4*)(W + i);
        float4 v1 = *(const float4*)(W + i + 4);
        *(bf16x8*)(wb + i) = cvt8(v0, v1);
    }
}

// ---------------- kernel 2: h[r] = bf16( xb[r] + sum_{c} xb[c] ) ------------
// TWO nodes per wave (2x memory-level parallelism); all front loads (both
// bucket lists, cnt int2, both residuals) issued in parallel with no serial
// chain; joint branchless 2-deep-per-node gather loop (4 outstanding loads),
// invalid slots masked via uniform-scalar fmaf scale instead of branches.
__global__ void k_agg(const float* __restrict__ x, const __bf16* __restrict__ xb,
                      const int* __restrict__ cnt, const int* __restrict__ bucket,
                      const int* __restrict__ ovf_cnt, const int2* __restrict__ ovf,
                      __bf16* __restrict__ h) {
    int w = (blockIdx.x * blockDim.x + threadIdx.x) >> 6;  // wave id; nodes 2w,2w+1
    if (w >= N_NODES / 2) return;
    int lane = threadIdx.x & 63;
    int gA = w * 2;
    int gB = gA + 1;
    const unsigned int* xbu = (const unsigned int*)xb;  // one bf16 pair per lane

    // ---- all independent front loads issue back-to-back ----
    const int* bkA = bucket + (size_t)gA * CAP;
    const int* bkB = bucket + (size_t)gB * CAP;
    int mA = (lane < CAP) ? bkA[lane] : 0;   // adjacency list A (garbage past deg ok)
    int mB = (lane < CAP) ? bkB[lane] : 0;   // adjacency list B
    int2 c2 = ((const int2*)cnt)[w];         // both degrees in one 8B load
    unsigned int rA = xbu[(size_t)gA * 64 + lane];  // residual A
    unsigned int rB = xbu[(size_t)gB * 64 + lane];  // residual B

    int degA = __builtin_amdgcn_readfirstlane(c2.x);
    int degB = __builtin_amdgcn_readfirstlane(c2.y);
    int dA = degA < CAP ? degA : CAP;
    int dB = degB < CAP ? degB : CAP;
    int dmax = dA > dB ? dA : dB;

    float aX0 = blo(rA), aY0 = bhi(rA), aX1 = 0.f, aY1 = 0.f;
    float bX0 = blo(rB), bY0 = bhi(rB), bX1 = 0.f, bY1 = 0.f;

    for (int d = 0; d < dmax; d += 2) {
        // uniform scalar selects: index 0 (valid row) + scale 0 when past deg
        int  cA0 = (d     < dA) ? __builtin_amdgcn_readlane(mA, d)     : 0;
        int  cA1 = (d + 1 < dA) ? __builtin_amdgcn_readlane(mA, d + 1) : 0;
        int  cB0 = (d     < dB) ? __builtin_amdgcn_readlane(mB, d)     : 0;
        int  cB1 = (d + 1 < dB) ? __builtin_amdgcn_readlane(mB, d + 1) : 0;
        float sA0 = (d     < dA) ? 1.f : 0.f;
        float sA1 = (d + 1 < dA) ? 1.f : 0.f;
        float sB0 = (d     < dB) ? 1.f : 0.f;
        float sB1 = (d + 1 < dB) ? 1.f : 0.f;
        unsigned int uA0 = xbu[(size_t)cA0 * 64 + lane];
        unsigned int uA1 = xbu[(size_t)cA1 * 64 + lane];
        unsigned int uB0 = xbu[(size_t)cB0 * 64 + lane];
        unsigned int uB1 = xbu[(size_t)cB1 * 64 + lane];
        aX0 = fmaf(sA0, blo(uA0), aX0); aY0 = fmaf(sA0, bhi(uA0), aY0);
        aX1 = fmaf(sA1, blo(uA1), aX1); aY1 = fmaf(sA1, bhi(uA1), aY1);
        bX0 = fmaf(sB0, blo(uB0), bX0); bY0 = fmaf(sB0, bhi(uB0), bY0);
        bX1 = fmaf(sB1, blo(uB1), bX1); bY1 = fmaf(sB1, bhi(uB1), bY1);
    }
    aX0 += aX1; aY0 += aY1;
    bX0 += bX1; bY0 += bY1;

    if (degA > CAP || degB > CAP) {  // statistically never; correctness fallback
        const float2* xr = (const float2*)x;
        int n = *ovf_cnt;
        if (n > OVF_CAP) n = OVF_CAP;
        for (int i = 0; i < n; ++i) {
            int2 e = ovf[i];
            if (e.x == gA) {
                float2 v = xr[(size_t)e.y * 64 + lane];
                aX0 += v.x; aY0 += v.y;
            }
            if (e.x == gB) {
                float2 v = xr[(size_t)e.y * 64 + lane];
                bX0 += v.x; bY0 += v.y;
            }
        }
    }

    bf16x2 oA = { (__bf16)aX0, (__bf16)aY0 };
    bf16x2 oB = { (__bf16)bX0, (__bf16)bY0 };
    ((bf16x2*)h)[(size_t)gA * 64 + lane] = oA;
    ((bf16x2*)h)[(size_t)gB * 64 + lane] = oB;
}

// ---------------- kernel 3: out = h @ W^T + b (bf16 MFMA) -------------------
#define BM 128
#define BN 128
#define LDA 136   // +8 pad: row stride 272B -> 2-way bank alias (free per m136)
#define LDB 136
#define NWG 3128  // 782 m-panels * 4 n-panels; 3128 = 8*391 (bijective swizzle)

__launch_bounds__(512, 4)
__global__ void k_gemm(const __bf16* __restrict__ h, const __bf16* __restrict__ wb,
                       const float* __restrict__ bias, float* __restrict__ out) {
    __shared__ __bf16 As[BM * LDA];  // 34816 B
    __shared__ __bf16 Bs[BN * LDB];  // 34816 B  (total ~70KB -> 2 blocks/CU)

    int tid = threadIdx.x;

    int bid = blockIdx.x;
    int wg = (bid & 7) * (NWG / 8) + (bid >> 3);
    int m0 = (wg >> 2) * BM;
    int n0 = (wg & 3) * BN;

    // stage A: 128x128 bf16, 16B loads
    #pragma unroll
    for (int it = 0; it < 4; ++it) {
        int i = tid + it * 512;
        int r = i >> 4;
        int c = (i & 15) << 3;
        int gr = m0 + r;
        if (gr > N_NODES - 1) gr = N_NODES - 1;
        *(bf16x8*)&As[r * LDA + c] = *(const bf16x8*)(h + (size_t)gr * D_IN + c);
    }
    // stage B: 128x128 bf16 W slice, 16B loads
    #pragma unroll
    for (int it = 0; it < 4; ++it) {
        int i = tid + it * 512;
        int r = i >> 4;
        int c = (i & 15) << 3;
        *(bf16x8*)&Bs[r * LDB + c] = *(const bf16x8*)(wb + (size_t)(n0 + r) * D_IN + c);
    }
    __syncthreads();

    int lane = tid & 63;
    int wave = tid >> 6;   // 0..7
    int wm = wave & 1;     // 2 waves along m (64 rows each)
    int wn = wave >> 1;    // 4 waves along n (32 cols each)
    int quad = lane >> 4;
    int l16 = lane & 15;

    f32x4 acc[4][2] = {};

    const __bf16* Abase = &As[(wm * 64 + l16) * LDA + quad * 8];
    const __bf16* Bbase = &Bs[(wn * 32 + l16) * LDB + quad * 8];

    #pragma unroll
    for (int ks = 0; ks < 4; ++ks) {
        bf16x8 a0 = *(const bf16x8*)(Abase + ks * 32);
        bf16x8 a1 = *(const bf16x8*)(Abase + 16 * LDA + ks * 32);
        bf16x8 a2 = *(const bf16x8*)(Abase + 32 * LDA + ks * 32);
        bf16x8 a3 = *(const bf16x8*)(Abase + 48 * LDA + ks * 32);
        bf16x8 b0 = *(const bf16x8*)(Bbase + ks * 32);
        bf16x8 b1 = *(const bf16x8*)(Bbase + 16 * LDB + ks * 32);
        acc[0][0] = __builtin_amdgcn_mfma_f32_16x16x32_bf16(a0, b0, acc[0][0], 0, 0, 0);
        acc[0][1] = __builtin_amdgcn_mfma_f32_16x16x32_bf16(a0, b1, acc[0][1], 0, 0, 0);
        acc[1][0] = __builtin_amdgcn_mfma_f32_16x16x32_bf16(a1, b0, acc[1][0], 0, 0, 0);
        acc[1][1] = __builtin_amdgcn_mfma_f32_16x16x32_bf16(a1, b1, acc[1][1], 0, 0, 0);
        acc[2][0] = __builtin_amdgcn_mfma_f32_16x16x32_bf16(a2, b0, acc[2][0], 0, 0, 0);
        acc[2][1] = __builtin_amdgcn_mfma_f32_16x16x32_bf16(a2, b1, acc[2][1], 0, 0, 0);
        acc[3][0] = __builtin_amdgcn_mfma_f32_16x16x32_bf16(a3, b0, acc[3][0], 0, 0, 0);
        acc[3][1] = __builtin_amdgcn_mfma_f32_16x16x32_bf16(a3, b1, acc[3][1], 0, 0, 0);
    }

    float bias0 = bias[n0 + wn * 32 + l16];
    float bias1 = bias[n0 + wn * 32 + 16 + l16];
    #pragma unroll
    for (int mt = 0; mt < 4; ++mt) {
        int mrow = m0 + wm * 64 + mt * 16 + quad * 4;
        #pragma unroll
        for (int nt = 0; nt < 2; ++nt) {
            int ncol = n0 + wn * 32 + nt * 16 + l16;
            float bv = nt ? bias1 : bias0;
            #pragma unroll
            for (int rg = 0; rg < 4; ++rg) {
                int m = mrow + rg;
                if (m < N_NODES)
                    __builtin_nontemporal_store(acc[mt][nt][rg] + bv,
                                                &out[(size_t)m * D_OUT + ncol]);
            }
        }
    }
}

extern "C" void kernel_launch(void* const* d_in, const int* in_sizes, int n_in,
                              void* d_out, int out_size, void* d_ws, size_t ws_size,
                              hipStream_t stream) {
    const float* x  = (const float*)d_in[0];
    const int*   ei = (const int*)d_in[1];
    const float* W  = (const float*)d_in[2];
    const float* b  = (const float*)d_in[3];
    float* out = (float*)d_out;

    char* ws = (char*)d_ws;
    __bf16* h    = (__bf16*)ws;
    int* cnt     = (int*)(ws + OFF_CNT);
    int* ovf_cnt = (int*)(ws + OFF_OVFC);
    int2* ovf    = (int2*)(ws + OFF_OVF);
    int* bucket  = (int*)(ws + OFF_BUCK);
    __bf16* xb   = (__bf16*)(ws + OFF_XB);
    __bf16* wb   = (__bf16*)(ws + OFF_WB);

    // zero cnt + ovf_cnt (contiguous region)
    hipMemsetAsync(cnt, 0, (OFF_OVFC - OFF_CNT) + 16, stream);

    k_bucket_cvt<<<EB + XB + WBK, 256, 0, stream>>>(ei, x, W, cnt, bucket,
                                                    ovf_cnt, ovf, xb, wb);
    k_agg<<<(N_NODES / 2 * 64 + 255) / 256, 256, 0, stream>>>(x, xb, cnt, bucket,
                                                              ovf_cnt, ovf, h);
    k_gemm<<<NWG, 512, 0, stream>>>(h, wb, b, out);
}